// Round 5
// baseline (304.280 us; speedup 1.0000x reference)
//
#include <hip/hip_runtime.h>

// MADE flow: u = (x - m)*exp(-a), logdet = -sum(a)
// B=524288, NI=32, H=128, NC=64.
// R7: amortize per-wave fixed overhead. R4 (100us) is spill-free (WRITE ==
// ideal 67584KB) but waves live ~14us vs ~1.5us of critical path -> per-wave
// startup latency dominates. Each wave now streams TWO 32-row tiles
// straight-line (no back-edge; R2 showed loop-carried ping-pong spills).
// Tile-1 acts prefetched after tile-0 bf cvt, converted to f16 right after
// L1 (frees 48 raw regs before the L2-phase register peak); tile-1 x is
// re-read in epilogue-1 (L3 hit) instead of held live. Peak ~148 regs ==
// R4's, under bounds(256,3)'s 170 budget -> no spill. Waves 16384->8192,
// one stage+barrier per 2 tiles.

#define B_ROWS 524288
#define NI 32
#define HD 128
#define NC 64

// K=32 fragments: 1 frag = 16(j) x 32(k) f16 = 512 halfs = 1KB
#define L2_BASE 24    // L1 frags: 8 jt * 3 kt = 24
#define L3_BASE 56    // L2 frags: 8 jt * 4 kt = 32
#define N_FRAGS 72    // L3 frags: 4 jt * 4 kt = 16

typedef _Float16 half8 __attribute__((ext_vector_type(8)));
typedef float f32x4 __attribute__((ext_vector_type(4)));

__device__ inline f32x4 relu4(f32x4 v) {
  v[0] = fmaxf(v[0], 0.f); v[1] = fmaxf(v[1], 0.f);
  v[2] = fmaxf(v[2], 0.f); v[3] = fmaxf(v[3], 0.f);
  return v;
}

__device__ inline half8 cvt8(f32x4 lo, f32x4 hi) {
  half8 h;
  h[0] = (_Float16)lo[0]; h[1] = (_Float16)lo[1];
  h[2] = (_Float16)lo[2]; h[3] = (_Float16)lo[3];
  h[4] = (_Float16)hi[0]; h[5] = (_Float16)hi[1];
  h[6] = (_Float16)hi[2]; h[7] = (_Float16)hi[3];
  return h;
}

// ---------------- prep: masked f16 weights in K=32 MFMA-A fragment order ----
// Fragment (frag, lane) holds A[m][k]: m = jt*16 + (lane&15),
// k = kt*32 + (e>>2)*16 + (lane>>4)*4 + (e&3)  (e=0..7, two stacked K=16
// halves). Stored at wf[frag*512 + lane*8 + e].
__global__ void prep_weights(const float* __restrict__ W1, const float* __restrict__ Wc,
                             const float* __restrict__ W2, const float* __restrict__ W3,
                             _Float16* __restrict__ wf) {
  int tid = blockIdx.x * blockDim.x + threadIdx.x;
  if (tid >= N_FRAGS * 64) return;
  int frag = tid >> 6;
  int lane = tid & 63;
  int q = lane >> 4, c = lane & 15;
  int L, jt, kt;
  if (frag < L2_BASE)      { L = 0; jt = frag / 3;              kt = frag % 3; }
  else if (frag < L3_BASE) { L = 1; jt = (frag - L2_BASE) >> 2; kt = (frag - L2_BASE) & 3; }
  else                     { L = 2; jt = (frag - L3_BASE) >> 2; kt = (frag - L3_BASE) & 3; }
  int j = jt * 16 + c;  // output unit (row of W)
  half8 v;
#pragma unroll
  for (int e = 0; e < 8; ++e) {
    int k = kt * 32 + (e >> 2) * 16 + q * 4 + (e & 3);
    float w;
    if (L == 0) {
      // layer1 K-dim is [x(32) | cond(64)]; mask m1 = (j%31 >= k), Wc unmasked
      if (k < NI) w = ((j % 31) >= k) ? W1[j * NI + k] : 0.f;
      else        w = Wc[j * NC + (k - NI)];
    } else if (L == 1) {
      w = ((j % 31) >= (k % 31)) ? W2[j * HD + k] : 0.f;          // m2
    } else {
      w = (((j % 32) - 1) >= (k % 31)) ? W3[j * HD + k] : 0.f;    // m3
    }
    v[e] = (_Float16)w;
  }
  *(half8*)(wf + (size_t)tid * 8) = v;
}

// ---------------- layer macros (weights: WPTR, frag index base FB) ----------
#define LAYER1(BF, H1)                                                        \
  _Pragma("unroll")                                                           \
  for (int jh = 0; jh < 2; ++jh) {                                            \
    _Pragma("unroll")                                                         \
    for (int j4 = 0; j4 < 4; ++j4) {                                          \
      f32x4 bv = *(const f32x4*)(b1 + (jh * 4 + j4) * 16 + q * 4);            \
      acc[j4][0] = bv; acc[j4][1] = bv;                                       \
    }                                                                         \
    _Pragma("unroll")                                                         \
    for (int j4 = 0; j4 < 4; ++j4) {                                          \
      int jt = jh * 4 + j4;                                                   \
      _Pragma("unroll")                                                       \
      for (int kt = 0; kt < 3; ++kt) {                                        \
        half8 a = *(const half8*)(wf + (((jt * 3 + kt) * 64 + lane) << 3));   \
        _Pragma("unroll")                                                     \
        for (int nt = 0; nt < 2; ++nt)                                        \
          acc[j4][nt] = __builtin_amdgcn_mfma_f32_16x16x32_f16(a, BF[kt][nt], acc[j4][nt], 0, 0, 0); \
      }                                                                       \
    }                                                                         \
    _Pragma("unroll")                                                         \
    for (int p = 0; p < 2; ++p)                                               \
      _Pragma("unroll")                                                       \
      for (int nt = 0; nt < 2; ++nt)                                          \
        H1[jh * 2 + p][nt] = cvt8(relu4(acc[p * 2][nt]), relu4(acc[p * 2 + 1][nt])); \
  }

#define LAYER2(H1, H2)                                                        \
  _Pragma("unroll")                                                           \
  for (int jh = 0; jh < 2; ++jh) {                                            \
    _Pragma("unroll")                                                         \
    for (int j4 = 0; j4 < 4; ++j4) {                                          \
      f32x4 bv = *(const f32x4*)(b2 + (jh * 4 + j4) * 16 + q * 4);            \
      acc[j4][0] = bv; acc[j4][1] = bv;                                       \
    }                                                                         \
    _Pragma("unroll")                                                         \
    for (int j4 = 0; j4 < 4; ++j4) {                                          \
      int jt = jh * 4 + j4;                                                   \
      _Pragma("unroll")                                                       \
      for (int kt = 0; kt < 4; ++kt) {                                        \
        half8 a = *(const half8*)(wlds + (((jt * 4 + kt) * 64 + lane) << 3)); \
        _Pragma("unroll")                                                     \
        for (int nt = 0; nt < 2; ++nt)                                        \
          acc[j4][nt] = __builtin_amdgcn_mfma_f32_16x16x32_f16(a, H1[kt][nt], acc[j4][nt], 0, 0, 0); \
      }                                                                       \
    }                                                                         \
    _Pragma("unroll")                                                         \
    for (int p = 0; p < 2; ++p)                                               \
      _Pragma("unroll")                                                       \
      for (int nt = 0; nt < 2; ++nt)                                          \
        H2[jh * 2 + p][nt] = cvt8(relu4(acc[p * 2][nt]), relu4(acc[p * 2 + 1][nt])); \
  }

#define LAYER3(H2)                                                            \
  _Pragma("unroll")                                                           \
  for (int jt = 0; jt < 4; ++jt) {                                            \
    f32x4 bv = *(const f32x4*)(b3 + jt * 16 + q * 4);                         \
    acc[jt][0] = bv; acc[jt][1] = bv;                                         \
  }                                                                           \
  _Pragma("unroll")                                                           \
  for (int jt = 0; jt < 4; ++jt)                                              \
    _Pragma("unroll")                                                         \
    for (int kt = 0; kt < 4; ++kt) {                                          \
      half8 a = *(const half8*)(wlds + (((32 + jt * 4 + kt) * 64 + lane) << 3)); \
      _Pragma("unroll")                                                       \
      for (int nt = 0; nt < 2; ++nt)                                          \
        acc[jt][nt] = __builtin_amdgcn_mfma_f32_16x16x32_f16(a, H2[kt][nt], acc[jt][nt], 0, 0, 0); \
    }

// epilogue: XA/XB give f32x4 x-slices for (nt, half) — expression with nt bound
#define EPILOGUE(TILEROW, XA, XB)                                             \
  _Pragma("unroll")                                                           \
  for (int nt = 0; nt < 2; ++nt) {                                            \
    long m = (TILEROW) + nt * 16 + c;                                         \
    f32x4 xa = XA, xb = XB;                                                   \
    f32x4 mva = acc[0][nt], mvb = acc[1][nt];                                 \
    f32x4 ava = acc[2][nt], avb = acc[3][nt];                                 \
    f32x4 ua, ub;                                                             \
    float s = 0.f;                                                            \
    _Pragma("unroll")                                                         \
    for (int i = 0; i < 4; ++i) {                                             \
      float aa = fminf(fmaxf(ava[i], -5.f), 5.f);                             \
      float ab = fminf(fmaxf(avb[i], -5.f), 5.f);                             \
      ua[i] = (xa[i] - mva[i]) * __expf(-aa);                                 \
      ub[i] = (xb[i] - mvb[i]) * __expf(-ab);                                 \
      s += aa + ab;                                                           \
    }                                                                         \
    *(f32x4*)(out + m * NI + q * 4) = ua;                                     \
    *(f32x4*)(out + m * NI + 16 + q * 4) = ub;                                \
    s += __shfl_xor(s, 16);                                                   \
    s += __shfl_xor(s, 32);                                                   \
    if (q == 0) out[(long)B_ROWS * NI + m] = -s;                              \
  }

// ---------------- fused main kernel ----------------
// 4 waves/block; each wave streams TWO tiles of 32 rows, straight-line.
// Grid = B/256 = 2048 blocks. bounds(256,3): 170-reg budget, no spill,
// 3 blocks/CU by LDS (3*48KB=144 <= 160KB).
__global__ __launch_bounds__(256, 3) void made_fused(
    const float* __restrict__ x, const float* __restrict__ cond,
    const float* __restrict__ b1, const float* __restrict__ b2,
    const float* __restrict__ b3, const _Float16* __restrict__ wf,
    float* __restrict__ out) {
  // L2+L3 weight fragments staged in LDS: frags 24..71 -> 48 * 1KB = 48KB
  __shared__ __align__(16) _Float16 wlds[48 * 512];

  const int tid  = threadIdx.x;
  const int lane = tid & 63;
  const int wid  = tid >> 6;
  const int q = lane >> 4, c = lane & 15;
  const long waveRow = ((long)blockIdx.x * 4 + wid) * 64;  // 64 rows/wave

  // ---- tile-0 activation loads FIRST (oldest vmcnt entries) ----
  f32x4 xv0[2][2], cv0[2][4];
#pragma unroll
  for (int nt = 0; nt < 2; ++nt) {
    const f32x4* xr = (const f32x4*)(x    + (waveRow + nt * 16 + c) * NI);
    const f32x4* cr = (const f32x4*)(cond + (waveRow + nt * 16 + c) * NC);
    xv0[nt][0] = xr[q];     xv0[nt][1] = xr[4 + q];
    cv0[nt][0] = cr[q];     cv0[nt][1] = cr[4 + q];
    cv0[nt][2] = cr[8 + q]; cv0[nt][3] = cr[12 + q];
  }

  // ---- one-time stage: 48KB L2/L3 weights via global_load_lds (12KB/wave) --
  {
    const char* gsrc = (const char*)(wf + L2_BASE * 512) + wid * 12288;
    char* ldst = (char*)wlds + wid * 12288;
#pragma unroll
    for (int i = 0; i < 12; ++i) {
      __builtin_amdgcn_global_load_lds(
          (const __attribute__((address_space(1))) void*)(gsrc + i * 1024 + lane * 16),
          (__attribute__((address_space(3))) void*)(ldst + i * 1024),
          16, 0, 0);
    }
  }

  // ---- body 0: tile 0 -------------------------------------------------
  half8 bf0[3][2];
#pragma unroll
  for (int nt = 0; nt < 2; ++nt) {
    bf0[0][nt] = cvt8(xv0[nt][0], xv0[nt][1]);
    bf0[1][nt] = cvt8(cv0[nt][0], cv0[nt][1]);
    bf0[2][nt] = cvt8(cv0[nt][2], cv0[nt][3]);
  }

  // prefetch tile-1 activations NOW (12KB in flight under body-0 compute)
  f32x4 xv1[2][2], cv1[2][4];
#pragma unroll
  for (int nt = 0; nt < 2; ++nt) {
    const f32x4* xr = (const f32x4*)(x    + (waveRow + 32 + nt * 16 + c) * NI);
    const f32x4* cr = (const f32x4*)(cond + (waveRow + 32 + nt * 16 + c) * NC);
    xv1[nt][0] = xr[q];     xv1[nt][1] = xr[4 + q];
    cv1[nt][0] = cr[q];     cv1[nt][1] = cr[4 + q];
    cv1[nt][2] = cr[8 + q]; cv1[nt][3] = cr[12 + q];
  }

  f32x4 acc[4][2];
  half8 h1[4][2], h2[4][2];

  LAYER1(bf0, h1);

  // convert tile-1 acts to f16 fragments (loads had all of L1 to arrive);
  // frees the 48 raw regs before the L2-phase register peak. tile-1 x will
  // be re-read at epilogue-1 (L3 hit) rather than held live.
  half8 bf1[3][2];
#pragma unroll
  for (int nt = 0; nt < 2; ++nt) {
    bf1[0][nt] = cvt8(xv1[nt][0], xv1[nt][1]);
    bf1[1][nt] = cvt8(cv1[nt][0], cv1[nt][1]);
    bf1[2][nt] = cvt8(cv1[nt][2], cv1[nt][3]);
  }

  __syncthreads();  // LDS weights ready (drains stage); the only barrier

  LAYER2(h1, h2);
  LAYER3(h2);
  EPILOGUE(waveRow, xv0[nt][0], xv0[nt][1]);

  // ---- body 1: tile 1 (no barrier; waves de-phase) --------------------
  LAYER1(bf1, h1);
  LAYER2(h1, h2);
  LAYER3(h2);
  EPILOGUE(waveRow + 32,
           (*(const f32x4*)(x + (waveRow + 32 + nt * 16 + c) * NI + q * 4)),
           (*(const f32x4*)(x + (waveRow + 32 + nt * 16 + c) * NI + 16 + q * 4)));
}

extern "C" void kernel_launch(void* const* d_in, const int* in_sizes, int n_in,
                              void* d_out, int out_size, void* d_ws, size_t ws_size,
                              hipStream_t stream) {
  const float* x    = (const float*)d_in[0];
  const float* cond = (const float*)d_in[1];
  const float* W1   = (const float*)d_in[2];
  const float* b1   = (const float*)d_in[3];
  const float* Wc   = (const float*)d_in[4];
  const float* W2   = (const float*)d_in[5];
  const float* b2   = (const float*)d_in[6];
  const float* W3   = (const float*)d_in[7];
  const float* b3   = (const float*)d_in[8];
  _Float16* wf = (_Float16*)d_ws;  // 72 frags * 512 halfs * 2B = 72 KB

  prep_weights<<<(N_FRAGS * 64 + 255) / 256, 256, 0, stream>>>(W1, Wc, W2, W3, wf);
  made_fused<<<B_ROWS / 256, 256, 0, stream>>>(x, cond, b1, b2, b3, wf, (float*)d_out);
}